// Round 4
// baseline (178.065 us; speedup 1.0000x reference)
//
#include <hip/hip_runtime.h>

// Problem constants (match reference)
constexpr int B = 128;
constexpr int N = 262144;
constexpr int CHUNKS = 16;                 // blocks per sample
constexpr int THREADS = 256;
constexpr int TOTAL_BLOCKS = B * CHUNKS;   // 2048
constexpr int V4_PER_SAMPLE = N / 4;       // 65536 float4 per class-row
constexpr int V4_PER_CHUNK = V4_PER_SAMPLE / CHUNKS;   // 4096
constexpr int ITERS = V4_PER_CHUNK / THREADS;          // 16

__device__ __forceinline__ void elem(float x0, float x1, int lv, float w,
                                     float& sum, int& npos) {
    float d  = x0 - x1;                    // p0 - p1
    float ad = fabsf(d);
    // t = log(1 + exp(-|d|)) — HW v_exp_f32 + v_log_f32 only
    float t  = __logf(1.0f + __expf(-ad));
    bool isPos = (lv != 0);
    float sd   = isPos ? d : -d;
    float coef = isPos ? w : 1.0f;
    sum  = fmaf(coef, fmaxf(sd, 0.0f) + t, sum);
    npos += lv;                            // labels are exactly 0/1
}

__global__ __launch_bounds__(THREADS) void ce_fused(
    const float* __restrict__ inp, const int* __restrict__ label,
    const float* __restrict__ weightp,
    float* __restrict__ ws_per, float* __restrict__ ws_npos,
    unsigned int* __restrict__ counter, float* __restrict__ out) {
    const int b = blockIdx.y;
    const int chunk = blockIdx.x;
    const float w = weightp[0];

    const float4* p0  = reinterpret_cast<const float4*>(inp + (size_t)b * 2 * N);
    const float4* p1  = reinterpret_cast<const float4*>(inp + (size_t)b * 2 * N + N);
    const int4*   lab = reinterpret_cast<const int4*>(label + (size_t)b * N);

    // ---- R2's proven inner loop, verbatim: compiler schedules this well ----
    float sum = 0.f;
    int   npos = 0;
    int base = chunk * V4_PER_CHUNK + threadIdx.x;
    #pragma unroll 4
    for (int i = 0; i < ITERS; ++i) {
        int idx = base + i * THREADS;
        float4 a = p0[idx];
        float4 c = p1[idx];
        int4   l = lab[idx];
        elem(a.x, c.x, l.x, w, sum, npos);
        elem(a.y, c.y, l.y, w, sum, npos);
        elem(a.z, c.z, l.z, w, sum, npos);
        elem(a.w, c.w, l.w, w, sum, npos);
    }

    float nposf = (float)npos;
    for (int o = 32; o > 0; o >>= 1) {
        sum   += __shfl_down(sum, o);
        nposf += __shfl_down(nposf, o);
    }
    __shared__ float red_s[THREADS / 64];
    __shared__ float red_n[THREADS / 64];
    __shared__ bool  amLast;
    const int lane = threadIdx.x & 63;
    const int wid  = threadIdx.x >> 6;
    if (lane == 0) { red_s[wid] = sum; red_n[wid] = nposf; }
    __syncthreads();
    if (threadIdx.x == 0) {
        float s = 0.f, n = 0.f;
        #pragma unroll
        for (int i = 0; i < THREADS / 64; ++i) { s += red_s[i]; n += red_n[i]; }
        const int slot = b * CHUNKS + chunk;
        ws_per[slot]  = s;
        ws_npos[slot] = n;
        __threadfence();                       // release partials device-wide
        unsigned int old = atomicAdd(counter, 1u);
        amLast = (old == TOTAL_BLOCKS - 1);
    }
    __syncthreads();

    if (amLast) {
        __threadfence();                       // acquire others' partials
        const int t = threadIdx.x;
        float ps = 0.f;
        if (t < B) {
            float sp = 0.f, np = 0.f;
            #pragma unroll
            for (int c = 0; c < CHUNKS; ++c) {
                sp += ws_per[t * CHUNKS + c];
                np += ws_npos[t * CHUNKS + c];
            }
            ps = sp / ((float)N + (w - 1.f) * np);
        }
        for (int o = 32; o > 0; o >>= 1) ps += __shfl_down(ps, o);
        __shared__ float red[THREADS / 64];
        if (lane == 0) red[wid] = ps;
        __syncthreads();
        if (t == 0) {
            float acc = 0.f;
            #pragma unroll
            for (int i = 0; i < THREADS / 64; ++i) acc += red[i];
            out[0] = acc / (float)B;
        }
    }
}

extern "C" void kernel_launch(void* const* d_in, const int* in_sizes, int n_in,
                              void* d_out, int out_size, void* d_ws, size_t ws_size,
                              hipStream_t stream) {
    const float* inp     = (const float*)d_in[0];
    const int*   label   = (const int*)d_in[1];
    const float* weightp = (const float*)d_in[2];
    float* out = (float*)d_out;

    float* ws_per  = (float*)d_ws;
    float* ws_npos = ws_per + TOTAL_BLOCKS;
    unsigned int* counter = (unsigned int*)(ws_npos + TOTAL_BLOCKS);

    // counter must start at 0 each launch (graph-safe async memset)
    hipMemsetAsync(counter, 0, sizeof(unsigned int), stream);

    dim3 grid(CHUNKS, B);
    ce_fused<<<grid, THREADS, 0, stream>>>(inp, label, weightp,
                                           ws_per, ws_npos, counter, out);
}

// Round 6
// 65.939 us; speedup vs baseline: 2.7005x; 2.7005x over previous
//
#include <hip/hip_runtime.h>

// Problem constants (match reference)
constexpr int B = 128;
constexpr int N = 262144;
constexpr int CHUNKS = 16;                 // blocks per sample
constexpr int THREADS = 256;
constexpr int V4_PER_SAMPLE = N / 4;       // 65536 float4 per class-row
constexpr int V4_PER_CHUNK = V4_PER_SAMPLE / CHUNKS;   // 4096
constexpr int ITERS = V4_PER_CHUNK / THREADS;          // 16

// native clang vectors (nontemporal builtin requires these, not HIP_vector_type)
typedef float f32x4 __attribute__((ext_vector_type(4)));
typedef int   i32x4 __attribute__((ext_vector_type(4)));

__device__ __forceinline__ void elem(float x0, float x1, int lv, float w,
                                     float& sum, int& npos) {
    float d  = x0 - x1;                    // p0 - p1
    float ad = fabsf(d);
    // t = log(1 + exp(-|d|)) — HW v_exp_f32 + v_log_f32 only
    float t  = __logf(1.0f + __expf(-ad));
    bool isPos = (lv != 0);
    float sd   = isPos ? d : -d;
    float coef = isPos ? w : 1.0f;
    sum  = fmaf(coef, fmaxf(sd, 0.0f) + t, sum);
    npos += lv;                            // labels are exactly 0/1
}

__global__ __launch_bounds__(THREADS) void ce_partial(
    const float* __restrict__ inp, const int* __restrict__ label,
    const float* __restrict__ weightp,
    float* __restrict__ ws_per, float* __restrict__ ws_npos) {
    const int b = blockIdx.y;
    const int chunk = blockIdx.x;
    const float w = weightp[0];

    const f32x4* p0  = reinterpret_cast<const f32x4*>(inp + (size_t)b * 2 * N);
    const f32x4* p1  = reinterpret_cast<const f32x4*>(inp + (size_t)b * 2 * N + N);
    const i32x4* lab = reinterpret_cast<const i32x4*>(label + (size_t)b * N);

    float sum = 0.f;
    int   npos = 0;
    int base = chunk * V4_PER_CHUNK + threadIdx.x;
    #pragma unroll 4
    for (int i = 0; i < ITERS; ++i) {
        int idx = base + i * THREADS;
        // streaming data (read exactly once): nontemporal -> global_load_* nt
        f32x4 a = __builtin_nontemporal_load(&p0[idx]);
        f32x4 c = __builtin_nontemporal_load(&p1[idx]);
        i32x4 l = __builtin_nontemporal_load(&lab[idx]);
        elem(a.x, c.x, l.x, w, sum, npos);
        elem(a.y, c.y, l.y, w, sum, npos);
        elem(a.z, c.z, l.z, w, sum, npos);
        elem(a.w, c.w, l.w, w, sum, npos);
    }

    float nposf = (float)npos;
    // wave reduce (64 lanes)
    for (int o = 32; o > 0; o >>= 1) {
        sum   += __shfl_down(sum, o);
        nposf += __shfl_down(nposf, o);
    }
    __shared__ float red_s[THREADS / 64];
    __shared__ float red_n[THREADS / 64];
    int lane = threadIdx.x & 63;
    int wid  = threadIdx.x >> 6;
    if (lane == 0) { red_s[wid] = sum; red_n[wid] = nposf; }
    __syncthreads();
    if (threadIdx.x == 0) {
        float s = 0.f, n = 0.f;
        #pragma unroll
        for (int i = 0; i < THREADS / 64; ++i) { s += red_s[i]; n += red_n[i]; }
        int slot = b * CHUNKS + chunk;
        ws_per[slot]  = s;
        ws_npos[slot] = n;
    }
}

__global__ __launch_bounds__(128) void ce_final(
    const float* __restrict__ ws_per, const float* __restrict__ ws_npos,
    const float* __restrict__ weightp, float* __restrict__ out) {
    const float w = weightp[0];
    int b = threadIdx.x;   // 128 threads, one per sample
    float sp = 0.f, np = 0.f;
    #pragma unroll
    for (int c = 0; c < CHUNKS; ++c) {
        sp += ws_per[b * CHUNKS + c];
        np += ws_npos[b * CHUNKS + c];
    }
    float ps = sp / ((float)N + (w - 1.f) * np);
    // reduce 128 threads = 2 waves
    for (int o = 32; o > 0; o >>= 1) ps += __shfl_down(ps, o);
    __shared__ float red[2];
    if ((threadIdx.x & 63) == 0) red[threadIdx.x >> 6] = ps;
    __syncthreads();
    if (threadIdx.x == 0) out[0] = (red[0] + red[1]) / (float)B;
}

extern "C" void kernel_launch(void* const* d_in, const int* in_sizes, int n_in,
                              void* d_out, int out_size, void* d_ws, size_t ws_size,
                              hipStream_t stream) {
    const float* inp     = (const float*)d_in[0];
    const int*   label   = (const int*)d_in[1];
    const float* weightp = (const float*)d_in[2];
    float* out = (float*)d_out;

    float* ws_per  = (float*)d_ws;
    float* ws_npos = ws_per + B * CHUNKS;

    dim3 grid(CHUNKS, B);
    ce_partial<<<grid, THREADS, 0, stream>>>(inp, label, weightp, ws_per, ws_npos);
    ce_final<<<1, 128, 0, stream>>>(ws_per, ws_npos, weightp, out);
}